// Round 2
// baseline (59.992 us; speedup 1.0000x reference)
//
#include <hip/hip_runtime.h>
#include <math.h>

// L = diag((W+W^T).sum(1)) - (W+W^T), W scattered from per-face cotangent weights.
// Strategy: bin contributions per-row into a compact COO workspace, then a
// single fused pass zeroes + merges + writes each 32KB row (the only pass
// touching the 256MB output).

#define CAP 256   // per-row bucket capacity; expected degree ~12 (Poisson), 256 is untouchable

__device__ __forceinline__ void load_face(const int* __restrict__ Fw, int f, bool is64,
                                          int& i0, int& i1, int& i2) {
    if (is64) {
        const int base = f * 6;
        i0 = Fw[base + 0]; i1 = Fw[base + 2]; i2 = Fw[base + 4];
    } else {
        const int base = f * 3;
        i0 = Fw[base + 0]; i1 = Fw[base + 1]; i2 = Fw[base + 2];
    }
}

__device__ __forceinline__ void cot_weights(const float* __restrict__ V,
                                            int i0, int i1, int i2,
                                            float& c0, float& c1, float& c2) {
    const float ax = V[i0 * 3 + 0], ay = V[i0 * 3 + 1], az = V[i0 * 3 + 2];
    const float bx = V[i1 * 3 + 0], by = V[i1 * 3 + 1], bz = V[i1 * 3 + 2];
    const float cx = V[i2 * 3 + 0], cy = V[i2 * 3 + 1], cz = V[i2 * 3 + 2];

    float dx, dy, dz, d2;
    dx = bx - cx; dy = by - cy; dz = bz - cz;
    d2 = dx * dx + dy * dy + dz * dz;
    const float l1 = (d2 > 0.0f) ? sqrtf(d2) : 0.0f;
    dx = cx - ax; dy = cy - ay; dz = cz - az;
    d2 = dx * dx + dy * dy + dz * dz;
    const float l2 = (d2 > 0.0f) ? sqrtf(d2) : 0.0f;
    dx = ax - bx; dy = ay - by; dz = az - bz;
    d2 = dx * dx + dy * dy + dz * dz;
    const float l3 = (d2 > 0.0f) ? sqrtf(d2) : 0.0f;

    const float sp = (l1 + l2 + l3) * 0.5f;
    const float s  = sp * (sp - l1) * (sp - l2) * (sp - l3);
    const float A  = (s > 0.0f) ? 2.0f * sqrtf(s) : 1.0f;

    c0 = ((l2 * l2 + l3 * l3 - l1 * l1) / A) * 0.25f; // (r=i1, c=i2)
    c1 = ((l1 * l1 + l3 * l3 - l2 * l2) / A) * 0.25f; // (r=i2, c=i0)
    c2 = ((l1 * l1 + l2 * l2 - l3 * l3) / A) * 0.25f; // (r=i0, c=i1)
}

__global__ void bin_faces_kernel(const float* __restrict__ V, const int* __restrict__ Fw,
                                 int* __restrict__ cnt, float* __restrict__ diag,
                                 int* __restrict__ cols, float* __restrict__ vals,
                                 int nF) {
    int f = blockIdx.x * blockDim.x + threadIdx.x;
    if (f >= nF) return;

    // int64 vs int32 layout detection (little-endian high words all zero)
    const bool is64 = (Fw[1] == 0) && (Fw[3] == 0) && (Fw[5] == 0) &&
                      (Fw[7] == 0) && (Fw[9] == 0) && (Fw[11] == 0);

    int i0, i1, i2;
    load_face(Fw, f, is64, i0, i1, i2);
    float c0, c1, c2;
    cot_weights(V, i0, i1, i2, c0, c1, c2);

    // scatter (r, c, v): row r gets (c, -v); row c gets (r, -v); diag[r]+=v; diag[c]+=v
    const int rr[3] = {i1, i2, i0};
    const int cc[3] = {i2, i0, i1};
    const float vv[3] = {c0, c1, c2};
#pragma unroll
    for (int t = 0; t < 3; ++t) {
        const int r = rr[t], c = cc[t];
        const float v = vv[t];
        int idx = atomicAdd(&cnt[r], 1);
        if (idx < CAP) { cols[(size_t)r * CAP + idx] = c; vals[(size_t)r * CAP + idx] = -v; }
        idx = atomicAdd(&cnt[c], 1);
        if (idx < CAP) { cols[(size_t)c * CAP + idx] = r; vals[(size_t)c * CAP + idx] = -v; }
        atomicAdd(&diag[r], v);
        atomicAdd(&diag[c], v);
    }
}

// One block per row: zero LDS row, merge bucket entries + diagonal via LDS
// atomics, stream out as coalesced float4. Single pass over the 256MB output.
__global__ void fill_rows_kernel(const int* __restrict__ cnt, const float* __restrict__ diag,
                                 const int* __restrict__ cols, const float* __restrict__ vals,
                                 float* __restrict__ L, int N) {
    extern __shared__ float srow[];
    const int row = blockIdx.x;
    const int tid = threadIdx.x;
    const int nv4 = N >> 2;

    float4* s4 = (float4*)srow;
    const float4 z = make_float4(0.f, 0.f, 0.f, 0.f);
    for (int j = tid; j < nv4; j += blockDim.x) s4[j] = z;
    __syncthreads();

    int k = cnt[row];
    if (k > CAP) k = CAP;
    for (int t = tid; t < k; t += blockDim.x)
        atomicAdd(&srow[cols[(size_t)row * CAP + t]], vals[(size_t)row * CAP + t]);
    if (tid == 0) atomicAdd(&srow[row], diag[row]);
    __syncthreads();

    float4* out = (float4*)(L + (size_t)row * (size_t)N);
    for (int j = tid; j < nv4; j += blockDim.x) out[j] = s4[j];
}

// Fallback (ws too small): zero output then scatter directly with global atomics.
__global__ void face_scatter_kernel(const float* __restrict__ V, const int* __restrict__ Fw,
                                    float* __restrict__ L, int nF, int N) {
    int f = blockIdx.x * blockDim.x + threadIdx.x;
    if (f >= nF) return;
    const bool is64 = (Fw[1] == 0) && (Fw[3] == 0) && (Fw[5] == 0) &&
                      (Fw[7] == 0) && (Fw[9] == 0) && (Fw[11] == 0);
    int i0, i1, i2;
    load_face(Fw, f, is64, i0, i1, i2);
    float c0, c1, c2;
    cot_weights(V, i0, i1, i2, c0, c1, c2);
    const int rr[3] = {i1, i2, i0};
    const int cc[3] = {i2, i0, i1};
    const float vv[3] = {c0, c1, c2};
    const size_t n = (size_t)N;
#pragma unroll
    for (int t = 0; t < 3; ++t) {
        const int r = rr[t], c = cc[t];
        const float v = vv[t];
        atomicAdd(&L[(size_t)r * n + c], -v);
        atomicAdd(&L[(size_t)c * n + r], -v);
        atomicAdd(&L[(size_t)r * n + r],  v);
        atomicAdd(&L[(size_t)c * n + c],  v);
    }
}

extern "C" void kernel_launch(void* const* d_in, const int* in_sizes, int n_in,
                              void* d_out, int out_size, void* d_ws, size_t ws_size,
                              hipStream_t stream) {
    const float* V = (const float*)d_in[0];
    const int* Fw  = (const int*)d_in[1];
    float* L       = (float*)d_out;

    const int N  = in_sizes[0] / 3;   // 8192 vertices
    const int nF = in_sizes[1] / 3;   // 16384 faces

    // Workspace layout: [cnt: N int][diag: N float][cols: N*CAP int][vals: N*CAP float]
    const size_t need = (size_t)N * 4 + (size_t)N * 4 +
                        (size_t)N * CAP * 4 + (size_t)N * CAP * 4;

    if (ws_size >= need) {
        int*   cnt  = (int*)d_ws;
        float* diag = (float*)((char*)d_ws + (size_t)N * 4);
        int*   cols = (int*)((char*)d_ws + (size_t)N * 8);
        float* vals = (float*)((char*)d_ws + (size_t)N * 8 + (size_t)N * CAP * 4);

        // zero counters + diagonal accumulators (64 KB)
        hipMemsetAsync(d_ws, 0, (size_t)N * 8, stream);

        const int block = 256;
        bin_faces_kernel<<<(nF + block - 1) / block, block, 0, stream>>>(
            V, Fw, cnt, diag, cols, vals, nF);

        fill_rows_kernel<<<N, block, (size_t)N * sizeof(float), stream>>>(
            cnt, diag, cols, vals, L, N);
    } else {
        hipMemsetAsync(d_out, 0, (size_t)out_size * sizeof(float), stream);
        const int block = 256;
        face_scatter_kernel<<<(nF + block - 1) / block, block, 0, stream>>>(V, Fw, L, nF, N);
    }
}